// Round 10
// baseline (437.859 us; speedup 1.0000x reference)
//
#include <hip/hip_runtime.h>

#define HH 256
#define WW 256
#define PAD 4
#define HW (HH * WW)

#define TW 32      // tile width (pixels)
#define TH 16      // tile height (pixels)
#define PR 20      // patch rows per pass = TH + 4
#define PC 40      // patch cols = TW + 8
#define PCP 41     // padded LDS col stride (proven conflict-free r4/r6)
#define NSPLIT 8   // channel splits across blocks
#define CPB 32     // channels per block
#define NG 8       // channel groups of 4 per block
#define NSLOT 4    // ceil(PR*PC / 256) staging slots per thread

// Tap geometry per pass, local kernel-rows lr = 0..4:
//   PASS 0: abs row R = lr;     tap cols [0, lr==4 ? 5 : 9)   -> taps 0..40
//   PASS 1: abs row R = lr + 4; tap cols [lr==0 ? 5 : 0, 9)   -> taps 41..80
__host__ __device__ constexpr int clo_f(int PASS, int lr) { return (PASS == 1 && lr == 0) ? 5 : 0; }
__host__ __device__ constexpr int chi_f(int PASS, int lr) { return (PASS == 0 && lr == 4) ? 5 : 9; }

__device__ __forceinline__ void fma4(float4& a, const float4& k, float w) {
    a.x = fmaf(k.x, w, a.x);
    a.y = fmaf(k.y, w, a.y);
    a.z = fmaf(k.z, w, a.z);
    a.w = fmaf(k.w, w, a.w);
}

template<int PASS>
__global__ __launch_bounds__(256, 4)
void prop_pass(const float* __restrict__ key, const float* __restrict__ wts,
               float* __restrict__ out) {
    // double-buffered key patch: [buf][row*PCP+col] float4 = 4 channels
    __shared__ float4 smem[2][PR * PCP];

    const int tid = threadIdx.x;
    const int tw  = tid & 15;   // w-pair 0..15
    const int th  = tid >> 4;   // h 0..15
    const int w0  = blockIdx.x * TW;
    const int h0  = blockIdx.y * TH;
    const int c0  = blockIdx.z * CPB;
    const int h   = h0 + th;
    const int w   = w0 + 2 * tw;

    // ---- per-pixel weights for this pass's taps (fixed-shape, DCE'd slots) ----
    float wt0[5][9], wt1[5][9];
    {
        const float* wp = wts + h * WW + w;   // w even -> 8B aligned
        #pragma unroll
        for (int lr = 0; lr < 5; ++lr) {
            #pragma unroll
            for (int c = 0; c < 9; ++c) {
                if (c >= clo_f(PASS, lr) && c < chi_f(PASS, lr)) {
                    const int t = (lr + 4 * PASS) * 9 + c;   // global tap index
                    float2 v = *reinterpret_cast<const float2*>(wp + (size_t)t * HW);
                    wt0[lr][c] = v.x;
                    wt1[lr][c] = v.y;
                }
            }
        }
    }

    // ---- hoisted staging state (computed ONCE) ----
    // patch input rows: gh = h0 - 4*(1-PASS) + row, row 0..PR-1
    const int gh0 = h0 - 4 * (1 - PASS);
    const float* sp[NSLOT];
    int  sdst[NSLOT];
    bool sin_[NSLOT];
    bool sact[NSLOT];
    #pragma unroll
    for (int k = 0; k < NSLOT; ++k) {
        int p    = tid + k * 256;
        bool act = p < PR * PC;
        int row  = p / PC;
        int col  = p - row * PC;
        int gh   = gh0 + row;
        int gw   = w0 - PAD + col;
        bool inb = act && (unsigned)gh < HH && (unsigned)gw < WW;
        sact[k] = act;
        sin_[k] = inb;
        sdst[k] = row * PCP + col;
        sp[k]   = key + (size_t)c0 * HW + (inb ? (gh * WW + gw) : 0);
    }

    // ---- prologue: stage channel-group 0 into buffer 0 ----
    {
        float4 v[NSLOT];
        #pragma unroll
        for (int k = 0; k < NSLOT; ++k) {
            const float* q = sp[k];
            v[k].x = q[0];
            v[k].y = q[HW];
            v[k].z = q[2 * HW];
            v[k].w = q[3 * HW];
            if (!sin_[k]) v[k] = make_float4(0.f, 0.f, 0.f, 0.f);
            sp[k] += 4 * HW;
        }
        #pragma unroll
        for (int k = 0; k < NSLOT; ++k)
            if (sact[k]) smem[0][sdst[k]] = v[k];
    }
    __syncthreads();

    float* op = out + (size_t)c0 * HW + h * WW + w;

    for (int g = 0; g < NG; ++g) {
        const bool pf = (g + 1 < NG);

        // 1) issue next-group staging loads into REGISTERS
        float4 stg[NSLOT];
        if (pf) {
            #pragma unroll
            for (int k = 0; k < NSLOT; ++k) {
                const float* q = sp[k];
                stg[k].x = q[0];
                stg[k].y = q[HW];
                stg[k].z = q[2 * HW];
                stg[k].w = q[3 * HW];
                if (!sin_[k]) stg[k] = make_float4(0.f, 0.f, 0.f, 0.f);
                sp[k] += 4 * HW;
            }
        }

        // 2) compute this pass's taps for 2 px x 4 ch
        //    patch row for (th, lr) = th + lr in both passes
        const float4* bp = &smem[g & 1][th * PCP + 2 * tw];
        float4 a0 = make_float4(0.f, 0.f, 0.f, 0.f);
        float4 a1 = make_float4(0.f, 0.f, 0.f, 0.f);
        #pragma unroll
        for (int lr = 0; lr < 5; ++lr) {
            #pragma unroll
            for (int cc = 0; cc <= 9; ++cc) {
                const int cl = clo_f(PASS, lr);
                const int ch = chi_f(PASS, lr);
                const bool u0 = (cc >= cl) && (cc < ch);        // a0 tap (lr, cc)
                const bool u1 = (cc - 1 >= cl) && (cc - 1 < ch); // a1 tap (lr, cc-1)
                if (u0 || u1) {
                    float4 k4 = bp[lr * PCP + cc];   // ds_read_b128, imm offset
                    if (u0) fma4(a0, k4, wt0[lr][cc]);
                    if (u1) fma4(a1, k4, wt1[lr][cc - 1]);
                }
            }
        }

        // 3) store/accumulate 2 px x 4 ch
        if (PASS == 0) {
            *reinterpret_cast<float2*>(op)          = make_float2(a0.x, a1.x);
            *reinterpret_cast<float2*>(op + HW)     = make_float2(a0.y, a1.y);
            *reinterpret_cast<float2*>(op + 2 * HW) = make_float2(a0.z, a1.z);
            *reinterpret_cast<float2*>(op + 3 * HW) = make_float2(a0.w, a1.w);
        } else {
            float2 o0 = *reinterpret_cast<float2*>(op);
            float2 o1 = *reinterpret_cast<float2*>(op + HW);
            float2 o2 = *reinterpret_cast<float2*>(op + 2 * HW);
            float2 o3 = *reinterpret_cast<float2*>(op + 3 * HW);
            *reinterpret_cast<float2*>(op)          = make_float2(o0.x + a0.x, o0.y + a1.x);
            *reinterpret_cast<float2*>(op + HW)     = make_float2(o1.x + a0.y, o1.y + a1.y);
            *reinterpret_cast<float2*>(op + 2 * HW) = make_float2(o2.x + a0.z, o2.y + a1.z);
            *reinterpret_cast<float2*>(op + 3 * HW) = make_float2(o3.x + a0.w, o3.y + a1.w);
        }
        op += 4 * HW;

        // 4) write staged regs to the other buffer (vmcnt wait lands HERE)
        if (pf) {
            #pragma unroll
            for (int k = 0; k < NSLOT; ++k)
                if (sact[k]) smem[(g + 1) & 1][sdst[k]] = stg[k];
        }

        // 5) single barrier per group
        __syncthreads();
    }
}

extern "C" void kernel_launch(void* const* d_in, const int* in_sizes, int n_in,
                              void* d_out, int out_size, void* d_ws, size_t ws_size,
                              hipStream_t stream) {
    const float* key = (const float*)d_in[0];   // (1,256,256,256) f32
    const float* wts = (const float*)d_in[1];   // (1,81,256,256)  f32
    float* out = (float*)d_out;                 // (1,256,256,256) f32

    dim3 grid(WW / TW, HH / TH, NSPLIT);        // 8 x 16 x 8 = 1024 blocks (4/CU)
    prop_pass<0><<<grid, 256, 0, stream>>>(key, wts, out);  // taps 0..40  -> out =
    prop_pass<1><<<grid, 256, 0, stream>>>(key, wts, out);  // taps 41..80 -> out +=
}

// Round 11
// 197.043 us; speedup vs baseline: 2.2221x; 2.2221x over previous
//
#include <hip/hip_runtime.h>

#define HH 256
#define WW 256
#define PAD 4
#define HW (HH * WW)

#define TW 32      // tile width (pixels)
#define TH 16      // tile height (pixels)
#define PR 24      // patch rows = TH + 8
#define PC 40      // patch cols = TW + 8
#define PCP 41     // padded LDS col stride (proven conflict-free r4/r6)
#define NSPLIT 8   // channel splits across blocks
#define CPB 32     // channels per block
#define NG 8       // channel groups of 4 per block
#define NSLOT 4    // ceil(PR*PC / 256) staging slots per thread

__device__ __forceinline__ void fma4(float4& a, const float4& k, float w) {
    a.x = fmaf(k.x, w, a.x);
    a.y = fmaf(k.y, w, a.y);
    a.z = fmaf(k.z, w, a.z);
    a.w = fmaf(k.w, w, a.w);
}

// pack two f32 -> bf16x2 (round-half-up); lo = a (pixel0), hi = b (pixel1)
__device__ __forceinline__ unsigned pack_bf16pair(float a, float b) {
    unsigned ua = (__float_as_uint(a) + 0x8000u) >> 16;
    unsigned ub = (__float_as_uint(b) + 0x8000u) >> 16;
    return ua | (ub << 16);
}
__device__ __forceinline__ float bf16_lo(unsigned p) { return __uint_as_float(p << 16); }
__device__ __forceinline__ float bf16_hi(unsigned p) { return __uint_as_float(p & 0xffff0000u); }

__global__ __launch_bounds__(256, 2)   // NEVER force 4: r8/r10 allocator collapse
void prop_kernel(const float* __restrict__ key, const float* __restrict__ wts,
                 float* __restrict__ out) {
    // double-buffered key patch: [buf][row*PCP+col] float4 = 4 channels
    __shared__ float4 smem[2][PR * PCP];

    const int tid = threadIdx.x;
    const int tw  = tid & 15;   // w-pair 0..15
    const int th  = tid >> 4;   // h 0..15
    const int w0  = blockIdx.x * TW;
    const int h0  = blockIdx.y * TH;
    const int c0  = blockIdx.z * CPB;
    const int h   = h0 + th;
    const int w   = w0 + 2 * tw;

    // ---- per-pixel weights, packed bf16x2 (px0|px1) -> 81 regs not 162 ----
    unsigned wt[81];
    {
        const float* wp = wts + h * WW + w;   // w even -> 8B aligned
        #pragma unroll
        for (int t = 0; t < 81; ++t) {
            float2 v = *reinterpret_cast<const float2*>(wp + (size_t)t * HW);
            wt[t] = pack_bf16pair(v.x, v.y);
        }
    }

    // ---- hoisted staging state (computed ONCE) ----
    const float* sp[NSLOT];
    int  sdst[NSLOT];
    bool sin_[NSLOT];
    bool sact[NSLOT];
    #pragma unroll
    for (int k = 0; k < NSLOT; ++k) {
        int p    = tid + k * 256;
        bool act = p < PR * PC;
        int row  = p / PC;
        int col  = p - row * PC;
        int gh   = h0 - PAD + row;
        int gw   = w0 - PAD + col;
        bool inb = act && (unsigned)gh < HH && (unsigned)gw < WW;
        sact[k] = act;
        sin_[k] = inb;
        sdst[k] = row * PCP + col;
        sp[k]   = key + (size_t)c0 * HW + (inb ? (gh * WW + gw) : 0);
    }

    // ---- prologue: stage channel-group 0 into buffer 0 ----
    {
        float4 v[NSLOT];
        #pragma unroll
        for (int k = 0; k < NSLOT; ++k) {
            const float* q = sp[k];
            v[k].x = q[0];
            v[k].y = q[HW];
            v[k].z = q[2 * HW];
            v[k].w = q[3 * HW];
            if (!sin_[k]) v[k] = make_float4(0.f, 0.f, 0.f, 0.f);
            sp[k] += 4 * HW;
        }
        #pragma unroll
        for (int k = 0; k < NSLOT; ++k)
            if (sact[k]) smem[0][sdst[k]] = v[k];
    }
    __syncthreads();

    float* op = out + (size_t)c0 * HW + h * WW + w;

    for (int g = 0; g < NG; ++g) {
        const bool pf = (g + 1 < NG);

        // 1) issue next-group staging loads into REGISTERS
        float4 stg[NSLOT];
        if (pf) {
            #pragma unroll
            for (int k = 0; k < NSLOT; ++k) {
                const float* q = sp[k];
                stg[k].x = q[0];
                stg[k].y = q[HW];
                stg[k].z = q[2 * HW];
                stg[k].w = q[3 * HW];
                if (!sin_[k]) stg[k] = make_float4(0.f, 0.f, 0.f, 0.f);
                sp[k] += 4 * HW;
            }
        }

        // 2) compute 2 px x 4 ch from current buffer
        const float4* bp = &smem[g & 1][th * PCP + 2 * tw];
        float4 a0 = make_float4(0.f, 0.f, 0.f, 0.f);
        float4 a1 = make_float4(0.f, 0.f, 0.f, 0.f);
        #pragma unroll
        for (int r = 0; r < 9; ++r) {
            #pragma unroll
            for (int c = 0; c < 10; ++c) {
                float4 k4 = bp[r * PCP + c];           // ds_read_b128, imm offset
                if (c < 9)  fma4(a0, k4, bf16_lo(wt[r * 9 + c]));
                if (c >= 1) fma4(a1, k4, bf16_hi(wt[r * 9 + c - 1]));
            }
        }

        // 3) store 2 px x 4 ch
        *reinterpret_cast<float2*>(op)          = make_float2(a0.x, a1.x);
        *reinterpret_cast<float2*>(op + HW)     = make_float2(a0.y, a1.y);
        *reinterpret_cast<float2*>(op + 2 * HW) = make_float2(a0.z, a1.z);
        *reinterpret_cast<float2*>(op + 3 * HW) = make_float2(a0.w, a1.w);
        op += 4 * HW;

        // 4) write staged regs to the other buffer (vmcnt wait lands HERE)
        if (pf) {
            #pragma unroll
            for (int k = 0; k < NSLOT; ++k)
                if (sact[k]) smem[(g + 1) & 1][sdst[k]] = stg[k];
        }

        // 5) single barrier per group
        __syncthreads();
    }
}

extern "C" void kernel_launch(void* const* d_in, const int* in_sizes, int n_in,
                              void* d_out, int out_size, void* d_ws, size_t ws_size,
                              hipStream_t stream) {
    const float* key = (const float*)d_in[0];   // (1,256,256,256) f32
    const float* wts = (const float*)d_in[1];   // (1,81,256,256)  f32
    float* out = (float*)d_out;                 // (1,256,256,256) f32

    dim3 grid(WW / TW, HH / TH, NSPLIT);        // 8 x 16 x 8 = 1024 blocks
    prop_kernel<<<grid, 256, 0, stream>>>(key, wts, out);
}